// Round 14
// baseline (258.799 us; speedup 1.0000x reference)
//
#include <hip/hip_runtime.h>
#include <hip/hip_bf16.h>

typedef __attribute__((ext_vector_type(8))) short bf16x8;
typedef __attribute__((ext_vector_type(4))) float f32x4;

#define KDIM 2048
#define BK 64
#define NT (KDIM / BK)   // 32 K-tiles

__device__ __forceinline__ unsigned short f2bf(float f) {
  union { float fv; unsigned int u; } c; c.fv = f;
  unsigned int u = c.u;
  unsigned int r = (u + 0x7FFFu + ((u >> 16) & 1u)) >> 16;
  return (unsigned short)r;
}

__device__ __forceinline__ void gload_lds16(const unsigned short* g, unsigned short* l) {
  auto gp = reinterpret_cast<const __attribute__((address_space(1))) unsigned int*>(
      reinterpret_cast<uintptr_t>(g));
  auto lp = reinterpret_cast<__attribute__((address_space(3))) unsigned int*>(
      reinterpret_cast<uintptr_t>(l));
  __builtin_amdgcn_global_load_lds(gp, lp, 16, 0, 0);
}

__device__ __forceinline__ float sigm(float z) { return 1.0f / (1.0f + __expf(-z)); }
__device__ __forceinline__ float tanh_fast(float z) { return 1.0f - 2.0f / (__expf(2.0f * z) + 1.0f); }

// Build hx = [x | h] as bf16 [4096][2048]
__global__ void pack_hx_kernel(const float* __restrict__ x, const float* __restrict__ h,
                               unsigned short* __restrict__ hx) {
  int idx = (blockIdx.x * blockDim.x + threadIdx.x) * 4;
  int row = idx >> 11;
  int col = idx & 2047;
  const float* src = (col < 1024) ? (x + (size_t)row * 1024 + col)
                                  : (h + (size_t)row * 1024 + (col - 1024));
  float4 v = *reinterpret_cast<const float4*>(src);
  ushort4 o = make_ushort4(f2bf(v.x), f2bf(v.y), f2bf(v.z), f2bf(v.w));
  *reinterpret_cast<ushort4*>(hx + idx) = o;
}

// All four W [2048][1024] f32 -> Wt [4][1024][2048] bf16 in one launch (z = gate)
__global__ void transpose_w4_kernel(const float* __restrict__ W0, const float* __restrict__ W1,
                                    const float* __restrict__ W2, const float* __restrict__ W3,
                                    unsigned short* __restrict__ Wt) {
  __shared__ float tile[32][33];
  const int g = blockIdx.z;
  const float* W = (g == 0) ? W0 : (g == 1) ? W1 : (g == 2) ? W2 : W3;
  unsigned short* T = Wt + (size_t)g * 1024 * 2048;
  int n0 = blockIdx.x * 32;
  int k0 = blockIdx.y * 32;
  int tx = threadIdx.x;
  int ty = threadIdx.y;
#pragma unroll
  for (int i = 0; i < 4; ++i)
    tile[ty + 8 * i][tx] = W[(size_t)(k0 + ty + 8 * i) * 1024 + (n0 + tx)];
  __syncthreads();
#pragma unroll
  for (int i = 0; i < 4; ++i)
    T[(size_t)(n0 + ty + 8 * i) * 2048 + (k0 + tx)] = f2bf(tile[tx][ty + 8 * i]);
}

#define BARR __builtin_amdgcn_s_barrier()
#define LGKM0 asm volatile("s_waitcnt lgkmcnt(0)" ::: "memory")
#define VMC(N) asm volatile("s_waitcnt vmcnt(" #N ")" ::: "memory")

// Issue one fragment set (12 ds_reads): 8 A-frags + 4 B-frags of one K-half.
#define RD_SET(AN, BN, ABUF, BBUF, CH)                                            \
  {                                                                               \
    _Pragma("unroll") for (int m = 0; m < 8; ++m)                                 \
      AN[m] = *reinterpret_cast<const bf16x8*>((ABUF) + aBase + m * 1024 + (CH) * 8); \
    _Pragma("unroll") for (int g = 0; g < 4; ++g)                                 \
      BN[g] = *reinterpret_cast<const bf16x8*>((BBUF) + bBase + g * 4096 + (CH) * 8); \
  }

// Consume one fragment set: 32 MFMA.
#define MM_SET(AN, BN)                                                            \
  __builtin_amdgcn_s_setprio(1);                                                  \
  _Pragma("unroll") for (int m = 0; m < 8; ++m)                                   \
    _Pragma("unroll") for (int g = 0; g < 4; ++g)                                 \
      acc[m][g] = __builtin_amdgcn_mfma_f32_16x16x32_bf16(AN[m], BN[g], acc[m][g], 0, 0, 0); \
  __builtin_amdgcn_s_setprio(0);

// Stage one K-tile (8 global_load_lds per thread) into buffer P.
#define STAGE(P)                                                                  \
  {                                                                               \
    _Pragma("unroll") for (int i = 0; i < 4; ++i)                                 \
      gload_lds16(srcA[i], &lA[P][dAB[i]]);                                       \
    _Pragma("unroll") for (int i = 0; i < 4; ++i)                                 \
      gload_lds16(srcB[i], &lB[P][dAB[i]]);                                       \
    _Pragma("unroll") for (int i = 0; i < 4; ++i) { srcA[i] += BK; srcB[i] += BK; } \
  }

// Fused 4-gate GEMM + LSTM epilogue — fragment-level double buffering:
// reads for set s+1 are issued BEFORE MFMA of set s (consume-from-registers).
// Grid: 256 blocks (1/CU), 512 threads (8 waves: 2 wr x 4 wc).
// Wave: 128 rows x 16 cols x 4 gates; per K-half: 12 ds_read_b128 -> 32 MFMA.
__global__ __launch_bounds__(512, 2) void lstm_fused_kernel(
    const unsigned short* __restrict__ hx,
    const unsigned short* __restrict__ wtb,
    const float* __restrict__ bias_f,
    const float* __restrict__ bias_i,
    const float* __restrict__ bias_s,
    const float* __restrict__ bias_p,
    const float* __restrict__ c_in,
    float* __restrict__ out) {
  __shared__ unsigned short lA[2][256 * BK];  // 2 x 32 KB : rows 0..255 (hx)
  __shared__ unsigned short lB[2][256 * BK];  // 2 x 32 KB : row = gate*64 + col

  const int tid  = threadIdx.x;
  const int lane = tid & 63;
  const int wid  = tid >> 6;
  const int wr   = wid >> 2;  // 0..1 : 128-row slice
  const int wc   = wid & 3;   // 0..3 : 16-col slice
  const int lg   = lane >> 4;
  const int ll   = lane & 15;

  // bijective XCD swizzle (256 % 8 == 0)
  const int wg   = (blockIdx.x & 7) * 32 + (blockIdx.x >> 3);
  const int brow = wg >> 4;  // 0..15
  const int bcol = wg & 15;  // 0..15

  // ---- staging descriptors (inverse-swizzled source, linear LDS dest) ----
  const unsigned short* srcA[4];
  const unsigned short* srcB[4];
  unsigned int dAB[4];
  {
    int r_lo = tid >> 3, sch = tid & 7;
    int ch = sch ^ (r_lo & 7);
#pragma unroll
    for (int i = 0; i < 4; ++i) {
      srcA[i] = hx + (size_t)(brow * 256 + i * 64 + r_lo) * KDIM + ch * 8;
      srcB[i] = wtb + (size_t)i * 1024 * 2048 + (size_t)(bcol * 64 + r_lo) * KDIM + ch * 8;
      dAB[i] = i * 4096 + tid * 8;
    }
  }

  // ---- fragment LDS element offsets ----
  const int ch0 = lg ^ (ll & 7);        // K-half 0 chunks
  const int ch1 = (4 + lg) ^ (ll & 7);  // K-half 1 chunks
  const unsigned aBase = (unsigned)((wr * 128 + ll) * 64);
  const unsigned bBase = (unsigned)((wc * 16 + ll) * 64);

  f32x4 acc[8][4];
#pragma unroll
  for (int m = 0; m < 8; ++m)
#pragma unroll
    for (int g = 0; g < 4; ++g)
      acc[m][g] = (f32x4)(0.0f);

  const unsigned short* A0 = &lA[0][0];
  const unsigned short* A1 = &lA[1][0];
  const unsigned short* B0 = &lB[0][0];
  const unsigned short* B1 = &lB[1][0];

  bf16x8 aS0[8], bS0[4];  // set A: K-half 0 of current tile
  bf16x8 aS1[8], bS1[4];  // set B: K-half 1 of current tile

  // ---- prologue: stage tiles 0,1; retire 0; preload set A = h0(tile0) ----
  STAGE(0)
  STAGE(1)
  VMC(8);  // tile 0 retired (8 of tile1 still in flight)
  BARR;
  RD_SET(aS0, bS0, A0, B0, ch0)

  for (int T = 0; T < NT; T += 2) {
    const bool s2 = (T + 2 < NT);

    // ===== w1(T): issue h1(T) reads; MFMA h0(T) from regs =====
    RD_SET(aS1, bS1, A0, B0, ch1)
    MM_SET(aS0, bS0)

    // ===== w2(T): sync point; issue h0(T+1) reads; stage T+2; MFMA h1(T) =====
    VMC(0);   // STAGE(T+1) retired (issued >=1 full tile ago)
    LGKM0;    // this wave's buf0 reads (h1 T) complete
    BARR;     // all waves: buf0 free to overwrite; T+1 data visible
    RD_SET(aS0, bS0, A1, B1, ch0)
    if (s2) STAGE(0)
    MM_SET(aS1, bS1)

    // ===== w1(T+1): issue h1(T+1) reads; MFMA h0(T+1) =====
    RD_SET(aS1, bS1, A1, B1, ch1)
    MM_SET(aS0, bS0)

    // ===== w2(T+1): sync point; issue h0(T+2) reads; stage T+3; MFMA h1(T+1) =====
    VMC(0);   // STAGE(T+2) retired (or no-op on last pair)
    LGKM0;    // buf1 reads (h1 T+1) complete
    BARR;
    if (s2) RD_SET(aS0, bS0, A0, B0, ch0)
    if (s2 && (T + 3 < NT)) STAGE(1)
    MM_SET(aS1, bS1)
  }

  // ---- epilogue: gates + cell update, store h_new (coalesced) ----
  const int col = bcol * 64 + wc * 16 + ll;
  const float bv0 = bias_f[col];
  const float bv1 = bias_i[col];
  const float bv2 = bias_s[col];
  const float bv3 = bias_p[col];
#pragma unroll
  for (int m = 0; m < 8; ++m) {
    const int rbase = brow * 256 + wr * 128 + m * 16 + lg * 4;
#pragma unroll
    for (int j = 0; j < 4; ++j) {
      int row = rbase + j;
      float zf = acc[m][0][j] + bv0;
      float zi = acc[m][1][j] + bv1;
      float zs = acc[m][2][j] + bv2;
      float zp = acc[m][3][j] + bv3;
      float fg = sigm(zf);
      float ig = sigm(zi);
      float sg = sigm(zs);
      float pg = tanh_fast(zp);
      float cn = c_in[(size_t)row * 1024 + col] * fg + ig * pg;
      out[(size_t)row * 1024 + col] = tanh_fast(cn) * sg;
    }
  }
}

extern "C" void kernel_launch(void* const* d_in, const int* in_sizes, int n_in,
                              void* d_out, int out_size, void* d_ws, size_t ws_size,
                              hipStream_t stream) {
  const float* x  = (const float*)d_in[0];
  const float* h  = (const float*)d_in[1];
  const float* c  = (const float*)d_in[2];
  const float* Wf = (const float*)d_in[3];
  const float* bf = (const float*)d_in[4];
  const float* Wi = (const float*)d_in[5];
  const float* bi = (const float*)d_in[6];
  const float* Ws = (const float*)d_in[7];
  const float* bs = (const float*)d_in[8];
  const float* Wp = (const float*)d_in[9];
  const float* bp = (const float*)d_in[10];
  float* out = (float*)d_out;

  unsigned short* ws = (unsigned short*)d_ws;
  unsigned short* hx  = ws;                        // 4096*2048 bf16 = 16 MB
  unsigned short* wtb = ws + (size_t)4096 * 2048;  // 4*1024*2048 bf16 = 16 MB

  pack_hx_kernel<<<(4096 * 2048 / 4) / 256, 256, 0, stream>>>(x, h, hx);

  dim3 tb(32, 8);
  dim3 tg(1024 / 32, 2048 / 32, 4);
  transpose_w4_kernel<<<tg, tb, 0, stream>>>(Wf, Wi, Ws, Wp, wtb);

  lstm_fused_kernel<<<256, 512, 0, stream>>>(hx, wtb, bf, bi, bs, bp, c, out);
}

// Round 15
// 93.338 us; speedup vs baseline: 2.7727x; 2.7727x over previous
//
#include <hip/hip_runtime.h>
#include <hip/hip_bf16.h>

typedef __attribute__((ext_vector_type(8))) short bf16x8;
typedef __attribute__((ext_vector_type(16))) float f32x16;

#define KDIM 2048
#define BK 64
#define NT (KDIM / BK)   // 32 K-tiles

__device__ __forceinline__ unsigned short f2bf(float f) {
  union { float fv; unsigned int u; } c; c.fv = f;
  unsigned int u = c.u;
  unsigned int r = (u + 0x7FFFu + ((u >> 16) & 1u)) >> 16;
  return (unsigned short)r;
}

__device__ __forceinline__ void gload_lds16(const unsigned short* g, unsigned short* l) {
  auto gp = reinterpret_cast<const __attribute__((address_space(1))) unsigned int*>(
      reinterpret_cast<uintptr_t>(g));
  auto lp = reinterpret_cast<__attribute__((address_space(3))) unsigned int*>(
      reinterpret_cast<uintptr_t>(l));
  __builtin_amdgcn_global_load_lds(gp, lp, 16, 0, 0);
}

__device__ __forceinline__ float sigm(float z) { return 1.0f / (1.0f + __expf(-z)); }
__device__ __forceinline__ float tanh_fast(float z) { return 1.0f - 2.0f / (__expf(2.0f * z) + 1.0f); }

// Build hx = [x | h] as bf16 [4096][2048]
__global__ void pack_hx_kernel(const float* __restrict__ x, const float* __restrict__ h,
                               unsigned short* __restrict__ hx) {
  int idx = (blockIdx.x * blockDim.x + threadIdx.x) * 4;
  int row = idx >> 11;
  int col = idx & 2047;
  const float* src = (col < 1024) ? (x + (size_t)row * 1024 + col)
                                  : (h + (size_t)row * 1024 + (col - 1024));
  float4 v = *reinterpret_cast<const float4*>(src);
  ushort4 o = make_ushort4(f2bf(v.x), f2bf(v.y), f2bf(v.z), f2bf(v.w));
  *reinterpret_cast<ushort4*>(hx + idx) = o;
}

// All four W [2048][1024] f32 -> Wt [4][1024][2048] bf16 in one launch (z = gate)
__global__ void transpose_w4_kernel(const float* __restrict__ W0, const float* __restrict__ W1,
                                    const float* __restrict__ W2, const float* __restrict__ W3,
                                    unsigned short* __restrict__ Wt) {
  __shared__ float tile[32][33];
  const int g = blockIdx.z;
  const float* W = (g == 0) ? W0 : (g == 1) ? W1 : (g == 2) ? W2 : W3;
  unsigned short* T = Wt + (size_t)g * 1024 * 2048;
  int n0 = blockIdx.x * 32;
  int k0 = blockIdx.y * 32;
  int tx = threadIdx.x;
  int ty = threadIdx.y;
#pragma unroll
  for (int i = 0; i < 4; ++i)
    tile[ty + 8 * i][tx] = W[(size_t)(k0 + ty + 8 * i) * 1024 + (n0 + tx)];
  __syncthreads();
#pragma unroll
  for (int i = 0; i < 4; ++i)
    T[(size_t)(n0 + ty + 8 * i) * 2048 + (k0 + tx)] = f2bf(tile[tx][ty + 8 * i]);
}

// Fused 4-gate GEMM + LSTM epilogue — 32x32x16 MFMA (half the instruction count).
// Grid: 256 blocks (1/CU), 512 threads (8 waves: 4 wr x 2 wc).
// Wave: 64 rows x 32 cols x 4 gates; per K-tile: 24 ds_read_b128 -> 32 MFMA.
__global__ __launch_bounds__(512, 2) void lstm_fused_kernel(
    const unsigned short* __restrict__ hx,
    const unsigned short* __restrict__ wtb,
    const float* __restrict__ bias_f,
    const float* __restrict__ bias_i,
    const float* __restrict__ bias_s,
    const float* __restrict__ bias_p,
    const float* __restrict__ c_in,
    float* __restrict__ out) {
  __shared__ unsigned short lA[2][256 * BK];  // 2 x 32 KB : rows 0..255 (hx)
  __shared__ unsigned short lB[2][256 * BK];  // 2 x 32 KB : row = gate*64 + col

  const int tid  = threadIdx.x;
  const int lane = tid & 63;
  const int wid  = tid >> 6;
  const int wr   = wid >> 1;   // 0..3 : 64-row slice
  const int wc   = wid & 1;    // 0..1 : 32-col slice
  const int lo5  = lane & 31;
  const int lh   = lane >> 5;  // 0..1
  const int l7   = lane & 7;

  // bijective XCD swizzle (256 % 8 == 0)
  const int wg   = (blockIdx.x & 7) * 32 + (blockIdx.x >> 3);
  const int brow = wg >> 4;  // 0..15
  const int bcol = wg & 15;  // 0..15

  // ---- staging: single base pointers + compile-time offsets (low VGPR) ----
  const unsigned short* srcA0;
  const unsigned short* srcB0;
  unsigned int dS;
  {
    int r_lo = tid >> 3, sch = tid & 7;
    int ch = sch ^ (r_lo & 7);  // inverse swizzle on global source
    srcA0 = hx + (size_t)(brow * 256 + r_lo) * KDIM + ch * 8;
    srcB0 = wtb + (size_t)(bcol * 64 + r_lo) * KDIM + ch * 8;
    dS = tid * 8;
  }
  // load i: A rows i*64.. -> +i*64*KDIM elems ; B gate i -> +i*1024*2048 elems
#define STAGE(P)                                                                   \
  {                                                                               \
    _Pragma("unroll") for (int i = 0; i < 4; ++i)                                 \
      gload_lds16(srcA0 + (size_t)i * 64 * KDIM, &lA[P][i * 4096 + dS]);          \
    _Pragma("unroll") for (int i = 0; i < 4; ++i)                                 \
      gload_lds16(srcB0 + (size_t)i * 1024 * 2048, &lB[P][i * 4096 + dS]);        \
    srcA0 += BK; srcB0 += BK;                                                     \
  }

  // ---- fragment LDS element offsets ----
  // A frag(m,ks): row = wr*64 + m*32 + lo5 ; k-chunk = (ks*2+lh) ^ (row&7)=l7
  // B frag(g,ks): row = g*64 + wc*32 + lo5 ; same chunk formula
  const unsigned aBase = (unsigned)((wr * 64 + lo5) * 64);
  const unsigned bBase = (unsigned)((wc * 32 + lo5) * 64);
  unsigned ck[4];
#pragma unroll
  for (int ks = 0; ks < 4; ++ks) ck[ks] = (unsigned)(((ks * 2 + lh) ^ l7) * 8);

  f32x16 acc[2][4];
#pragma unroll
  for (int m = 0; m < 2; ++m)
#pragma unroll
    for (int g = 0; g < 4; ++g)
      acc[m][g] = (f32x16)(0.0f);

  // ---- prologue ----
  STAGE(0)
  __syncthreads();

  for (int t = 0; t < NT; ++t) {
    const int p = t & 1;
    if (t < NT - 1) STAGE(p ^ 1)

    bf16x8 aF[2][4], bF[4][4];
#pragma unroll
    for (int m = 0; m < 2; ++m)
#pragma unroll
      for (int ks = 0; ks < 4; ++ks)
        aF[m][ks] = *reinterpret_cast<const bf16x8*>(&lA[p][aBase + m * 2048 + ck[ks]]);
#pragma unroll
    for (int g = 0; g < 4; ++g)
#pragma unroll
      for (int ks = 0; ks < 4; ++ks)
        bF[g][ks] = *reinterpret_cast<const bf16x8*>(&lB[p][g * 4096 + bBase + ck[ks]]);

    __builtin_amdgcn_s_setprio(1);
#pragma unroll
    for (int ks = 0; ks < 4; ++ks)      // ks-outer: 8 independent accs per group
#pragma unroll
      for (int m = 0; m < 2; ++m)
#pragma unroll
        for (int g = 0; g < 4; ++g)
          acc[m][g] = __builtin_amdgcn_mfma_f32_32x32x16_bf16(
              aF[m][ks], bF[g][ks], acc[m][g], 0, 0, 0);
    __builtin_amdgcn_s_setprio(0);

    __syncthreads();  // drains staging vmcnt + publishes; all waves done reading p
  }

  // ---- epilogue: C/D map col=lane&31, row=(j&3)+8*(j>>2)+4*lh ----
  const int col = bcol * 64 + wc * 32 + lo5;
  const float bv0 = bias_f[col];
  const float bv1 = bias_i[col];
  const float bv2 = bias_s[col];
  const float bv3 = bias_p[col];
#pragma unroll
  for (int m = 0; m < 2; ++m) {
    const int rb = brow * 256 + wr * 64 + m * 32 + 4 * lh;
#pragma unroll
    for (int j = 0; j < 16; ++j) {
      int row = rb + (j & 3) + 8 * (j >> 2);
      float zf = acc[m][0][j] + bv0;
      float zi = acc[m][1][j] + bv1;
      float zs = acc[m][2][j] + bv2;
      float zp = acc[m][3][j] + bv3;
      float fg = sigm(zf);
      float ig = sigm(zi);
      float sg = sigm(zs);
      float pg = tanh_fast(zp);
      float cn = c_in[(size_t)row * 1024 + col] * fg + ig * pg;
      out[(size_t)row * 1024 + col] = tanh_fast(cn) * sg;
    }
  }
}

extern "C" void kernel_launch(void* const* d_in, const int* in_sizes, int n_in,
                              void* d_out, int out_size, void* d_ws, size_t ws_size,
                              hipStream_t stream) {
  const float* x  = (const float*)d_in[0];
  const float* h  = (const float*)d_in[1];
  const float* c  = (const float*)d_in[2];
  const float* Wf = (const float*)d_in[3];
  const float* bf = (const float*)d_in[4];
  const float* Wi = (const float*)d_in[5];
  const float* bi = (const float*)d_in[6];
  const float* Ws = (const float*)d_in[7];
  const float* bs = (const float*)d_in[8];
  const float* Wp = (const float*)d_in[9];
  const float* bp = (const float*)d_in[10];
  float* out = (float*)d_out;

  unsigned short* ws = (unsigned short*)d_ws;
  unsigned short* hx  = ws;                        // 4096*2048 bf16 = 16 MB
  unsigned short* wtb = ws + (size_t)4096 * 2048;  // 4*1024*2048 bf16 = 16 MB

  pack_hx_kernel<<<(4096 * 2048 / 4) / 256, 256, 0, stream>>>(x, h, hx);

  dim3 tb(32, 8);
  dim3 tg(1024 / 32, 2048 / 32, 4);
  transpose_w4_kernel<<<tg, tb, 0, stream>>>(Wf, Wi, Ws, Wp, wtb);

  lstm_fused_kernel<<<256, 512, 0, stream>>>(hx, wtb, bf, bi, bs, bp, c, out);
}